// Round 7
// baseline (204.554 us; speedup 1.0000x reference)
//
#include <hip/hip_runtime.h>

#define DEVINL __device__ __forceinline__

typedef float f4v __attribute__((ext_vector_type(4)));

DEVINL float fmax4(float4 v) { return fmaxf(fmaxf(v.x, v.y), fmaxf(v.z, v.w)); }
DEVINL float4 max44(float4 a, float4 b) {
    float4 r; r.x = fmaxf(a.x, b.x); r.y = fmaxf(a.y, b.y);
    r.z = fmaxf(a.z, b.z); r.w = fmaxf(a.w, b.w); return r;
}

// Non-temporal (no-allocate) load/store for single-use streams.
// R10 proved nt lifts the ~2.6 TB/s L1-allocate service cap (225->201 total).
// NOTE: the builtin requires clang ext-vector types, not HIP_vector_type.
DEVINL float4 ntld(const float* p) {
    f4v r = __builtin_nontemporal_load((const f4v*)p);
    return *(float4*)&r;
}
DEVINL void ntst(float4 v, float* p) {
    __builtin_nontemporal_store(*(f4v*)&v, (f4v*)p);
}

// Compile-time memory barrier: pins issue order; loads above cannot sink.
#define MEMBAR() asm volatile("" ::: "memory")

// ---------------- R12: R6 two-kernel structure + nt policy ----------------
// R6 (verified, absmax 0) has 6720 pool waves (~26/CU, full CU coverage) vs
// the fused kernel's 8/CU on 224 CUs. It was capped by the same L1 service
// limit nt removes. Single-use data (t1..t4, ff, out) is nt; ws stays cached
// (6 MB -> L2/L3 hit on the combine re-read).
//
// ws float offsets: p1[8][128][28][28] @0, p2[8][64][28][28] @802816,
//                   p3[8][32][28][28] @1204224, p4[8][16][28][28] @1404928
#define O1 0
#define O2 802816
#define O3 1204224
#define O4 1404928
#define WS_FLOATS 1505280

// wave-class boundaries (wave id w)
#define WE4 3584    // t4: 3584 waves, 1 task (4 chunks) each
#define WE3 5376    // t3: 1792 waves x 4 tasks
#define WE2 6272    // t2:  896 waves x 4 tasks
#define WE1 6720    // t1m: 448 waves x 4 merged-tasks
// grid = 6720/4 = 1680 blocks

#define LD7(DST, PTR)                                                      \
    { _Pragma("unroll") for (int k = 0; k < 7; ++k)                        \
          DST[k] = ntld((PTR) + k * 256); }

__global__ __launch_bounds__(256, 4) void pool_all(
    const float* __restrict__ t1, const float* __restrict__ t2,
    const float* __restrict__ t3, const float* __restrict__ t4,
    float* __restrict__ ws)
{
    __shared__ __align__(16) float scratch[4 * 896];
    const int tid  = threadIdx.x;
    const int lane = tid & 63;
    const int w    = blockIdx.x * 4 + (tid >> 6);
    float* sm = &scratch[(tid >> 6) * 896];

    if (w < WE4) {
        // -------- t4 k=16: one task = 4 chunks (4 rows x 448 each) --------
        // chunk pos p=k*64+lane: r=p/112 (row-in-chunk), col4=p%112.
        const float* base = t4 + (size_t)w * 7168 + 4 * lane;
        float4 A[7], B[7], acc[7];
        LD7(A, base);                 // chunk 0
        LD7(B, base + 1792);          // chunk 1
        MEMBAR();
        #pragma unroll
        for (int k = 0; k < 7; ++k) acc[k] = A[k];
        LD7(A, base + 3584);          // chunk 2
        MEMBAR();
        #pragma unroll
        for (int k = 0; k < 7; ++k) acc[k] = max44(acc[k], B[k]);
        LD7(B, base + 5376);          // chunk 3
        MEMBAR();
        #pragma unroll
        for (int k = 0; k < 7; ++k) acc[k] = max44(acc[k], A[k]);
        #pragma unroll
        for (int k = 0; k < 7; ++k) acc[k] = max44(acc[k], B[k]);
        // identity LDS write (coalesced): sm[p] = col4-max over 16 rows/4
        #pragma unroll
        for (int k = 0; k < 7; ++k) sm[k * 64 + lane] = fmax4(acc[k]);
        MEMBAR();
        // out col j <- col4 4j..4j+3, row classes 0..3
        if (lane < 28) {
            float4 a = *(const float4*)&sm[0 * 112 + 4 * lane];
            float4 b = *(const float4*)&sm[1 * 112 + 4 * lane];
            float4 c = *(const float4*)&sm[2 * 112 + 4 * lane];
            float4 d = *(const float4*)&sm[3 * 112 + 4 * lane];
            ws[O4 + w * 28 + lane] =
                fmax4(max44(max44(a, b), max44(c, d)));
        }
    } else if (w < WE3) {
        // -------- t3 k=8: 4 independent tasks (8 rows x 224 each) --------
        // p=k*64+lane: row=p/56, col4=p%56. out col j <- col4 {2j,2j+1}.
        const int t0 = (w - WE4) * 4;
        const float* base = t3 + (size_t)t0 * 1792 + 4 * lane;
        float4 A[7], B[7];
        LD7(A, base);
        LD7(B, base + 1792);
        MEMBAR();
        #define T3_UNIT(VV, i)                                                 \
        {                                                                      \
            float* smh = sm + ((i) & 1) * 448;                                 \
            _Pragma("unroll") for (int k = 0; k < 7; ++k)                      \
                smh[k * 64 + lane] = fmax4(VV[k]);                             \
            if ((i) + 2 < 4) LD7(VV, base + ((i) + 2) * 1792);                 \
            MEMBAR();                                                          \
            if (lane < 28) {                                                   \
                float m = fmaxf(smh[2 * lane], smh[2 * lane + 1]);             \
                _Pragma("unroll") for (int r = 1; r < 8; ++r)                  \
                    m = fmaxf(m, fmaxf(smh[r * 56 + 2 * lane],                 \
                                       smh[r * 56 + 2 * lane + 1]));           \
                ws[O3 + (t0 + (i)) * 28 + lane] = m;                           \
            }                                                                  \
        }
        T3_UNIT(A, 0)
        T3_UNIT(B, 1)
        T3_UNIT(A, 2)
        T3_UNIT(B, 3)
    } else if (w < WE2) {
        // -------- t2 k=4: 4 independent tasks (16 rows x 112 each) --------
        // p=k*64+lane: row=p/28, pc=p%28 (one float4 = one 4-col window).
        const int t0 = (w - WE3) * 4;
        const float* base = t2 + (size_t)t0 * 1792 + 4 * lane;
        float4 A[7], B[7];
        LD7(A, base);
        LD7(B, base + 1792);
        MEMBAR();
        #define T2_UNIT(VV, i)                                                 \
        {                                                                      \
            float* smh = sm + ((i) & 1) * 448;                                 \
            _Pragma("unroll") for (int k = 0; k < 7; ++k)                      \
                smh[k * 64 + lane] = fmax4(VV[k]);                             \
            if ((i) + 2 < 4) LD7(VV, base + ((i) + 2) * 1792);                 \
            MEMBAR();                                                          \
            if (lane < 56) {                                                   \
                const int pr0 = lane / 28, pc = lane % 28;                     \
                _Pragma("unroll") for (int h = 0; h < 2; ++h) {                \
                    const int pr = pr0 + 2 * h;                                \
                    float m = fmaxf(fmaxf(smh[(4 * pr + 0) * 28 + pc],         \
                                          smh[(4 * pr + 1) * 28 + pc]),        \
                                    fmaxf(smh[(4 * pr + 2) * 28 + pc],         \
                                          smh[(4 * pr + 3) * 28 + pc]));       \
                    ws[O2 + (t0 + (i)) * 112 + pr * 28 + pc] = m;              \
                }                                                              \
            }                                                                  \
        }
        T2_UNIT(A, 0)
        T2_UNIT(B, 1)
        T2_UNIT(A, 2)
        T2_UNIT(B, 3)
    } else {
        // -------- t1 k=2: 4 merged-tasks, each = 32 rows x 56 cols --------
        // float4 idx p=k*64+lane (0..447): r=p/14, c=p%14 -> half-max pairs
        // sm[r*28+2c]=max(x,y), +1=max(z,w). Gather: out idx (q*28+j):
        // max(sm[q*56+j], sm[q*56+28+j]); 448 outputs, 7/lane (all 64).
        const int t0 = (w - WE2) * 4;
        const float* base = t1 + (size_t)t0 * 1792 + 4 * lane;
        float4 A[7], B[7];
        LD7(A, base);
        LD7(B, base + 1792);
        MEMBAR();
        #define T1_UNIT(VV, i)                                                 \
        {                                                                      \
            _Pragma("unroll") for (int k = 0; k < 7; ++k) {                    \
                const int p = k * 64 + lane;                                   \
                const int r = p / 14, c = p % 14;                              \
                float2 h;                                                      \
                h.x = fmaxf(VV[k].x, VV[k].y);                                 \
                h.y = fmaxf(VV[k].z, VV[k].w);                                 \
                *(float2*)&sm[r * 28 + 2 * c] = h;                             \
            }                                                                  \
            if ((i) + 2 < 4) LD7(VV, base + ((i) + 2) * 1792);                 \
            MEMBAR();                                                          \
            _Pragma("unroll") for (int h = 0; h < 7; ++h) {                    \
                const int idx = h * 64 + lane;                                 \
                const int q = idx / 28, j = idx % 28;                          \
                ws[O1 + (t0 + (i)) * 448 + idx] =                              \
                    fmaxf(sm[q * 56 + j], sm[q * 56 + j + 28]);                \
            }                                                                  \
        }
        T1_UNIT(A, 0)
        T1_UNIT(B, 1)
        T1_UNIT(A, 2)
        T1_UNIT(B, 3)
    }
}

__global__ __launch_bounds__(256) void combine(
    const float* __restrict__ ws, const float* __restrict__ ff,
    float* __restrict__ out)
{
    const int i4 = blockIdx.x * 256 + threadIdx.x;   // out float4 index
    const int pw4 = i4 % 7;
    const int ph  = (i4 / 7) % 28;
    const int c   = (i4 / 196) % 256;
    const int b   = i4 / 50176;
    const int ppw = ph * 7 + pw4;
    const float4* W = (const float4*)ws;
    // ws reads stay cached (6 MB -> L2/L3 hits); ff/out are nt single-use.
    float4 a1 = W[O1 / 4 + (b * 128 + (c & 127)) * 196 + ppw];
    float4 a2 = W[O2 / 4 + (b * 64  + (c & 63))  * 196 + ppw];
    float4 a3 = W[O3 / 4 + (b * 32  + (c & 31))  * 196 + ppw];
    float4 a4 = W[O4 / 4 + (b * 16  + (c & 15))  * 196 + ppw];
    float4 f  = ntld((const float*)ff + (size_t)i4 * 4);
    float4 o;
    o.x = fmaxf(a1.x + a2.x + a3.x + a4.x + f.x, 0.0f);
    o.y = fmaxf(a1.y + a2.y + a3.y + a4.y + f.y, 0.0f);
    o.z = fmaxf(a1.z + a2.z + a3.z + a4.z + f.z, 0.0f);
    o.w = fmaxf(a1.w + a2.w + a3.w + a4.w + f.w, 0.0f);
    ntst(o, (float*)out + (size_t)i4 * 4);
}

// ---------------- fallback (single-kernel) if ws too small ----------------
__global__ __launch_bounds__(256) void fused_pool_relu(
    const float* __restrict__ t1, const float* __restrict__ t2,
    const float* __restrict__ t3, const float* __restrict__ t4,
    const float* __restrict__ ff, float* __restrict__ out)
{
    const int pwq = blockIdx.x, ph = blockIdx.y, b = blockIdx.z;
    const int tid = threadIdx.x;
    const int pw0 = pwq * 4;
    __shared__ __align__(16) float p1[128 * 4];
    __shared__ __align__(16) float p2[64 * 4];
    __shared__ __align__(16) float p3[32 * 4];
    __shared__ __align__(16) float p4[16 * 4];
    {
        const int g = tid >> 4, l = tid & 15;
        const float* base = t4 + ((size_t)(b * 16 + g) * 448 + ph * 16) * 448
                          + pw0 * 16 + l * 4;
        float4 v[8];
        #pragma unroll
        for (int r = 0; r < 8; ++r) v[r] = *(const float4*)(base + r * 448);
        float4 acc = v[0];
        #pragma unroll
        for (int r = 1; r < 8; ++r) acc = max44(acc, v[r]);
        #pragma unroll
        for (int r = 8; r < 16; ++r) v[r - 8] = *(const float4*)(base + r * 448);
        #pragma unroll
        for (int r = 0; r < 8; ++r) acc = max44(acc, v[r]);
        float m = fmax4(acc);
        m = fmaxf(m, __shfl_xor(m, 1));
        m = fmaxf(m, __shfl_xor(m, 2));
        if ((l & 3) == 0) p4[g * 4 + (l >> 2)] = m;
    }
    {
        const int g = tid >> 3, l = tid & 7;
        const float* base = t3 + ((size_t)(b * 32 + g) * 224 + ph * 8) * 224
                          + pw0 * 8 + l * 4;
        float4 v[8];
        #pragma unroll
        for (int r = 0; r < 8; ++r) v[r] = *(const float4*)(base + r * 224);
        float4 acc = v[0];
        #pragma unroll
        for (int r = 1; r < 8; ++r) acc = max44(acc, v[r]);
        float m = fmax4(acc);
        m = fmaxf(m, __shfl_xor(m, 1));
        if ((l & 1) == 0) p3[g * 4 + (l >> 1)] = m;
    }
    {
        const int g = tid >> 2, l = tid & 3;
        const float* base = t2 + ((size_t)(b * 64 + g) * 112 + ph * 4) * 112
                          + pw0 * 4 + l * 4;
        float4 v[4];
        #pragma unroll
        for (int r = 0; r < 4; ++r) v[r] = *(const float4*)(base + r * 112);
        p2[g * 4 + l] = fmax4(max44(max44(v[0], v[1]), max44(v[2], v[3])));
    }
    {
        const int g = tid >> 1, l = tid & 1;
        const float* base = t1 + ((size_t)(b * 128 + g) * 56 + ph * 2) * 56
                          + pw0 * 2 + l * 4;
        float4 a = max44(*(const float4*)(base), *(const float4*)(base + 56));
        p1[g * 4 + l * 2 + 0] = fmaxf(a.x, a.y);
        p1[g * 4 + l * 2 + 1] = fmaxf(a.z, a.w);
    }
    __syncthreads();
    const int c = tid;
    const int o4 = (b * 200704 + c * 784 + ph * 28 + pw0) >> 2;
    const float4 f  = ((const float4*)ff)[o4];
    const float4 a1 = *(const float4*)&p1[(c & 127) * 4];
    const float4 a2 = *(const float4*)&p2[(c & 63) * 4];
    const float4 a3 = *(const float4*)&p3[(c & 31) * 4];
    const float4 a4 = *(const float4*)&p4[(c & 15) * 4];
    float4 o;
    o.x = fmaxf(a1.x + a2.x + a3.x + a4.x + f.x, 0.0f);
    o.y = fmaxf(a1.y + a2.y + a3.y + a4.y + f.y, 0.0f);
    o.z = fmaxf(a1.z + a2.z + a3.z + a4.z + f.z, 0.0f);
    o.w = fmaxf(a1.w + a2.w + a3.w + a4.w + f.w, 0.0f);
    ((float4*)out)[o4] = o;
}

extern "C" void kernel_launch(void* const* d_in, const int* in_sizes, int n_in,
                              void* d_out, int out_size, void* d_ws, size_t ws_size,
                              hipStream_t stream) {
    const float* t1 = (const float*)d_in[0];
    const float* t2 = (const float*)d_in[1];
    const float* t3 = (const float*)d_in[2];
    const float* t4 = (const float*)d_in[3];
    const float* ff = (const float*)d_in[4];
    float* out = (float*)d_out;

    if (ws_size >= (size_t)WS_FLOATS * sizeof(float)) {
        float* ws = (float*)d_ws;
        pool_all<<<WE1 / 4, 256, 0, stream>>>(t1, t2, t3, t4, ws);
        combine<<<1568, 256, 0, stream>>>(ws, ff, out);
    } else {
        dim3 grid(7, 28, 8);
        fused_pool_relu<<<grid, 256, 0, stream>>>(t1, t2, t3, t4, ff, out);
    }
}

// Round 8
// 200.071 us; speedup vs baseline: 1.0224x; 1.0224x over previous
//
#include <hip/hip_runtime.h>

#define DEVINL __device__ __forceinline__

typedef float f4 __attribute__((ext_vector_type(4)));

DEVINL float fmax4(f4 v) { return fmaxf(fmaxf(v.x, v.y), fmaxf(v.z, v.w)); }
DEVINL f4 max44(f4 a, f4 b) {
    f4 r; r.x = fmaxf(a.x, b.x); r.y = fmaxf(a.y, b.y);
    r.z = fmaxf(a.z, b.z); r.w = fmaxf(a.w, b.w); return r;
}

// ---------------- R13: R8 asm-pinned deep pipeline + nt policy ----------------
// R10/R12 proved nt lifts the ~2.6 TB/s L1-allocate cap (225 -> 200.7 total;
// fused ~56us). R8 proved the 14-21-deep asm load ledger is architecturally
// pinned (VGPR 88, passed). This round combines them: nt loads always go to
// L2/L3 (~600-900ns), so the builtin version's compiler-cut ~7-deep pipeline
// supports only ~3.7 TB/s; the pinned 14-21-deep ledger should reach ~5+.
//
// Async load: result regs NOT valid until a VMW() wait executes.
DEVINL f4 ald(const float* p) {
    f4 r;
    asm volatile("global_load_dwordx4 %0, %1, off nt" : "=v"(r) : "v"(p));
    return r;
}
// Counted wait + full scheduling fence (rule 18: sched_barrier stops the
// compiler hoisting register-only consumers above the wait).
#define VMW(N)                                                             \
    asm volatile("s_waitcnt vmcnt(" #N ")" ::: "memory");                  \
    __builtin_amdgcn_sched_barrier(0);

// Geometry identical to R7/R8 (verified, absmax 0): block (ph,b), 8 waves.
//   wave ww owns: t4 ch {2ww,2ww+1} (4 units each), t3 ch {4ww..4ww+3},
//   t2 ch {8ww..8ww+7} (2 packed units), t1 ch {16ww..16ww+15} (1 packed).
// unit = 1792 contiguous-per-lane floats = 7 asm loads.
//
// LDS float layout: P4@0[448] P3@448[896] P2@1344[1792] P1@3136[3584]
//                   scratch@6720: 8 waves x 896
#define P4O 0
#define P3O 448
#define P2O 1344
#define P1O 3136
#define SCRO 6720
#define LDS_FLOATS 13888   // 55.5 KB

#define LD7G(DST, PTR)                                                     \
    { _Pragma("unroll") for (int k = 0; k < 7; ++k)                        \
          DST[k] = ald((PTR) + k * 256); }

// t2 unit: 4 channels x 448 contiguous floats; f=k*64+lane: ch=f/112, q=f%112
#define LD7T2(DST, EOFF)                                                   \
    { _Pragma("unroll") for (int k = 0; k < 7; ++k) {                      \
          const int f = k * 64 + lane;                                     \
          DST[k] = ald(base2 + (EOFF) + (f / 112) * 12544 + (f % 112) * 4); } }

// t1 unit: 16 channels x 112 contiguous floats; ch=f/28, q=f%28
#define LD7T1(DST)                                                         \
    { _Pragma("unroll") for (int k = 0; k < 7; ++k) {                      \
          const int f = k * 64 + lane;                                     \
          DST[k] = ald(base1 + (f / 28) * 3136 + (f % 28) * 4); } }

#define ACCSET(V) { _Pragma("unroll") for (int k = 0; k < 7; ++k) acc[k] = V[k]; }
#define ACCMAX(V) { _Pragma("unroll") for (int k = 0; k < 7; ++k) acc[k] = max44(acc[k], V[k]); }

// t4 gather: sm[f] = max over 16 rows (residue r=f/112), out j = max r,q=4j..
#define GATH4(E)                                                           \
    { _Pragma("unroll") for (int k = 0; k < 7; ++k)                        \
          sm[k * 64 + lane] = fmax4(acc[k]);                               \
      if (lane < 28) {                                                     \
          f4 ga = *(const f4*)&sm[0 * 112 + 4 * lane];                     \
          f4 gb = *(const f4*)&sm[1 * 112 + 4 * lane];                     \
          f4 gc = *(const f4*)&sm[2 * 112 + 4 * lane];                     \
          f4 gd = *(const f4*)&sm[3 * 112 + 4 * lane];                     \
          lds[P4O + (2 * ww + (E)) * 28 + lane] =                          \
              fmax4(max44(max44(ga, gb), max44(gc, gd))); } }

// t3: sm[f] = row (f/56) col4 (f%56) max; out j = max 8 rows x col4 {2j,2j+1}
#define T3W(V, H)                                                          \
    { float* smh = sm + (H) * 448;                                         \
      _Pragma("unroll") for (int k = 0; k < 7; ++k)                        \
          smh[k * 64 + lane] = fmax4(V[k]); }
#define T3G(I, H)                                                          \
    { float* smh = sm + (H) * 448;                                         \
      if (lane < 28) {                                                     \
          float2 p0 = *(const float2*)&smh[2 * lane];                      \
          float m = fmaxf(p0.x, p0.y);                                     \
          _Pragma("unroll") for (int r = 1; r < 8; ++r) {                  \
              float2 pr = *(const float2*)&smh[r * 56 + 2 * lane];         \
              m = fmaxf(m, fmaxf(pr.x, pr.y)); }                          \
          lds[P3O + (4 * ww + (I)) * 28 + lane] = m; } }

// t2: sm[f] = per-row col4 max; out (cc,j) = max over 4 rows.
#define T2W(V, H)                                                          \
    { float* smh = sm + (H) * 448;                                         \
      _Pragma("unroll") for (int k = 0; k < 7; ++k)                        \
          smh[k * 64 + lane] = fmax4(V[k]); }
#define T2G(E, H)                                                          \
    { float* smh = sm + (H) * 448;                                         \
      if (lane < 56) {                                                     \
          _Pragma("unroll") for (int h2 = 0; h2 < 2; ++h2) {               \
              const int o = lane + 56 * h2;                                \
              const int cc = o / 28, j = o % 28;                           \
              float m = fmaxf(fmaxf(smh[cc * 112 + 0 * 28 + j],            \
                                    smh[cc * 112 + 1 * 28 + j]),           \
                              fmaxf(smh[cc * 112 + 2 * 28 + j],            \
                                    smh[cc * 112 + 3 * 28 + j]));          \
              lds[P2O + (8 * ww + 4 * (E) + cc) * 28 + j] = m; } } }

// t1: half-max pairs sm[2f],sm[2f+1] == [cc][row][outcol]; gather row pairs.
#define T1W(V)                                                             \
    { _Pragma("unroll") for (int k = 0; k < 7; ++k) {                      \
          const int f = k * 64 + lane;                                     \
          float2 hh; hh.x = fmaxf(V[k].x, V[k].y);                         \
          hh.y = fmaxf(V[k].z, V[k].w);                                    \
          *(float2*)&sm[2 * f] = hh; } }
#define T1G()                                                              \
    { _Pragma("unroll") for (int h2 = 0; h2 < 7; ++h2) {                   \
          const int idx = h2 * 64 + lane;                                  \
          const int cc = idx / 28, j = idx % 28;                           \
          lds[P1O + (16 * ww + cc) * 28 + j] =                             \
              fmaxf(sm[cc * 56 + j], sm[cc * 56 + 28 + j]); } }

__global__ __launch_bounds__(512, 2) void fused_all(
    const float* __restrict__ t1, const float* __restrict__ t2,
    const float* __restrict__ t3, const float* __restrict__ t4,
    const float* __restrict__ ff, float* __restrict__ out)
{
    __shared__ __align__(16) float lds[LDS_FLOATS];
    const int tid  = threadIdx.x;
    const int lane = tid & 63;
    const int ww   = tid >> 6;          // 0..7
    const int ph   = blockIdx.x;        // 0..27
    const int b    = blockIdx.y;        // 0..7
    float* sm = &lds[SCRO + ww * 896];

    // ---- ff preload, issued FIRST (oldest -> cancels out of all unit wait
    // counts). ffr regs valid after the final VMW(0). ----
    const float* FF = (const float*)ff;
    f4 ffr[4];
    #pragma unroll
    for (int m = 0; m < 4; ++m) {
        const int i4r = tid + 512 * m;
        const int i4 = i4r < 1792 ? i4r : 1791;   // clamp: uniform 4 loads/wave
        ffr[m] = ald(FF + ((size_t)(b * 256 + i4 / 7) * 196 + ph * 7 + i4 % 7) * 4);
    }

    // per-wave bases
    const float* a4 = t4 + (size_t)b * 3211264 + (2 * ww) * 200704
                    + ph * 16 * 448 + 4 * lane;          // t4 ch 2ww
    const float* b4 = a4 + 200704;                       // t4 ch 2ww+1
    const float* c3 = t3 + (size_t)b * 1605632 + (4 * ww) * 50176
                    + ph * 8 * 224 + 4 * lane;           // t3 ch 4ww..4ww+3
    const float* base2 = t2 + (size_t)b * 802816 + (8 * ww) * 12544
                       + ph * 448;                       // t2 ch 8ww..8ww+7
    const float* base1 = t1 + (size_t)b * 401408 + (16 * ww) * 3136
                       + ph * 112;                       // t1 ch 16ww..16ww+15

    f4 A[7], B[7], C[7], acc[7];
    // unit issue ledger (unit loads only; ffr x4 are older and retire first):
    LD7G(A, a4);                //  1-7   t4 chA u0
    LD7G(B, a4 + 1792);         //  8-14  t4 chA u1
    LD7G(C, a4 + 3584);         // 15-21  t4 chA u2
    VMW(14) ACCSET(A);          // A=u0 ready (21-14=7 oldest done)
    LD7G(A, a4 + 5376);         // 22-28  t4 chA u3
    VMW(14) ACCMAX(B);          // B=u1 (28-14=14)
    LD7G(B, b4);                // 29-35  t4 chB u0
    VMW(14) ACCMAX(C);          // C=u2 (35-14=21)
    LD7G(C, b4 + 1792);         // 36-42  t4 chB u1
    VMW(14) ACCMAX(A);          // A=u3 (42-14=28)
    LD7G(A, b4 + 3584);         // 43-49  t4 chB u2
    GATH4(0);
    VMW(14) ACCSET(B);          // B=chB u0 (49-14=35)
    LD7G(B, b4 + 5376);         // 50-56  t4 chB u3
    VMW(14) ACCMAX(C);          // C=chB u1 (56-14=42)
    LD7G(C, c3);                // 57-63  t3 c0
    VMW(14) ACCMAX(A);          // A=chB u2 (63-14=49)
    LD7G(A, c3 + 50176);        // 64-70  t3 c1
    VMW(14) ACCMAX(B);          // B=chB u3 (70-14=56)
    LD7G(B, c3 + 2 * 50176);    // 71-77  t3 c2
    GATH4(1);
    VMW(14) T3W(C, 0);          // C=c0 (77-14=63)
    LD7G(C, c3 + 3 * 50176);    // 78-84  t3 c3
    T3G(0, 0);
    VMW(14) T3W(A, 1);          // A=c1 (84-14=70)
    LD7T2(A, 0);                // 85-91  t2 d0
    T3G(1, 1);
    VMW(14) T3W(B, 0);          // B=c2 (91-14=77)
    LD7T2(B, 50176);            // 92-98  t2 d1
    T3G(2, 0);
    VMW(14) T3W(C, 1);          // C=c3 (98-14=84)
    LD7T1(C);                   // 99-105 t1 e0
    T3G(3, 1);
    VMW(14) T2W(A, 0);          // A=d0 (105-14=91)
    T2G(0, 0);
    VMW(7)  T2W(B, 1);          // B=d1 (105-7=98)
    T2G(1, 1);
    VMW(0)  T1W(C);             // C=e0 + ffr all complete
    T1G();

    __syncthreads();

    // ---- epilogue: out[b,:,ph,:] = relu(p1+p2+p3+p4+ff), nt stores ----
    f4* O = (f4*)out;
    #pragma unroll
    for (int m = 0; m < 4; ++m) {
        if (m < 3 || tid < 256) {
            const int i4 = tid + 512 * m;        // 0..1791
            const int ch = i4 / 7, j4 = i4 % 7;
            const f4 x1 = *(const f4*)&lds[P1O + (ch & 127) * 28 + 4 * j4];
            const f4 x2 = *(const f4*)&lds[P2O + (ch & 63)  * 28 + 4 * j4];
            const f4 x3 = *(const f4*)&lds[P3O + (ch & 31)  * 28 + 4 * j4];
            const f4 x4 = *(const f4*)&lds[P4O + (ch & 15)  * 28 + 4 * j4];
            const f4 f  = ffr[m];
            f4 o;
            o.x = fmaxf(x1.x + x2.x + x3.x + x4.x + f.x, 0.0f);
            o.y = fmaxf(x1.y + x2.y + x3.y + x4.y + f.y, 0.0f);
            o.z = fmaxf(x1.z + x2.z + x3.z + x4.z + f.z, 0.0f);
            o.w = fmaxf(x1.w + x2.w + x3.w + x4.w + f.w, 0.0f);
            __builtin_nontemporal_store(o, &O[(size_t)(b * 256 + ch) * 196 + ph * 7 + j4]);
        }
    }
}

extern "C" void kernel_launch(void* const* d_in, const int* in_sizes, int n_in,
                              void* d_out, int out_size, void* d_ws, size_t ws_size,
                              hipStream_t stream) {
    const float* t1 = (const float*)d_in[0];
    const float* t2 = (const float*)d_in[1];
    const float* t3 = (const float*)d_in[2];
    const float* t4 = (const float*)d_in[3];
    const float* ff = (const float*)d_in[4];
    dim3 grid(28, 8);
    fused_all<<<grid, 512, 0, stream>>>(t1, t2, t3, t4, ff, (float*)d_out);
}